// Round 1
// baseline (308.952 us; speedup 1.0000x reference)
//
#include <hip/hip_runtime.h>
#include <hip/hip_bf16.h>
#include <math.h>

typedef __bf16 bf16x8 __attribute__((ext_vector_type(8)));
typedef float f32x4 __attribute__((ext_vector_type(4)));

#define B_DIM 8
#define S_DIM 512
#define D_DIM 768
#define NC 8921
#define N_PAD 8960
#define TILE_N 64
#define N_TILES 140
#define NKCH 24
#define LDS_STRIDE 40
#define MASK_BYTES 16384

// ---- mask prep: sniff dtype (bool8 / int32 / float32) and emit 0/-inf bias
__global__ void prep_mask_kernel(const unsigned char* __restrict__ raw, float* __restrict__ bias) {
  __shared__ int s_ms, s_f32;
  int tid = threadIdx.x;
  if (tid == 0) { s_ms = 0; s_f32 = 0; }
  __syncthreads();
  int ms = 0, f32c = 0;
  for (int i = tid; i < B_DIM * S_DIM; i += 256) {
    unsigned char c = raw[i];
    if ((i & 3) != 0 && c != 0) ms++;
    if ((i & 3) == 3 && c == 0x3F) f32c++;
  }
  atomicAdd(&s_ms, ms);
  atomicAdd(&s_f32, f32c);
  __syncthreads();
  int mode = (s_ms == 0) ? 0 : ((s_f32 > 500) ? 2 : 1); // 0=int32 1=bool8 2=float32
  for (int i = tid; i < B_DIM * S_DIM; i += 256) {
    bool m;
    if (mode == 0)      m = ((const int*)raw)[i] != 0;
    else if (mode == 1) m = raw[i] != 0;
    else                m = ((const float*)raw)[i] != 0.0f;
    bias[i] = m ? 0.0f : -INFINITY;
  }
}

// ---- f32 -> bf16 conversion with zero padding past nvalid (nvalid % 8 == 0)
__global__ void cvt_kernel(const float* __restrict__ src, __bf16* __restrict__ dst, long nvalid) {
  long i = ((long)blockIdx.x * blockDim.x + threadIdx.x) * 8;
  bf16x8 o;
  if (i + 8 <= nvalid) {
    float4 a = *reinterpret_cast<const float4*>(src + i);
    float4 b = *reinterpret_cast<const float4*>(src + i + 4);
    o[0] = (__bf16)a.x; o[1] = (__bf16)a.y; o[2] = (__bf16)a.z; o[3] = (__bf16)a.w;
    o[4] = (__bf16)b.x; o[5] = (__bf16)b.y; o[6] = (__bf16)b.z; o[7] = (__bf16)b.w;
  } else {
#pragma unroll
    for (int j = 0; j < 8; ++j) o[j] = (__bf16)0.0f;
  }
  *reinterpret_cast<bf16x8*>(dst + i) = o;
}

// ---- fused: L = Q*E^T (scaled,masked), softmax rows, W out, logits = sum W*(CW*E^T)
__launch_bounds__(512, 2)
__global__ void fused_kernel(const float* __restrict__ E32, const float* __restrict__ Q32,
                             const float* __restrict__ W32,
                             const __bf16* __restrict__ Eb, const __bf16* __restrict__ Qb,
                             const __bf16* __restrict__ Wb,
                             const float* __restrict__ bias, float* __restrict__ out, int preconv) {
  __shared__ __attribute__((aligned(16))) __bf16 sE[S_DIM][LDS_STRIDE];
  __shared__ __attribute__((aligned(16))) __bf16 sQ[TILE_N][LDS_STRIDE];
  __shared__ __attribute__((aligned(16))) __bf16 sC[TILE_N][LDS_STRIDE];
  __shared__ float redA[4][TILE_N];
  __shared__ float redB[4][TILE_N];

  const int bid = blockIdx.x;
  const int b = bid & 7;          // batch -> XCD affinity (E slice L2-resident)
  const int nbase = (bid >> 3) * TILE_N;

  const int tid = threadIdx.x;
  const int lane = tid & 63;
  const int wave = tid >> 6;
  const int wm = wave >> 2;   // M half (0..1)
  const int wsl = wave & 3;   // S slice (0..3)
  const int l15 = lane & 15;
  const int lg = lane >> 4;

  f32x4 accL[2][8], accG[2][8];
  f32x4 zero = {0.f, 0.f, 0.f, 0.f};
#pragma unroll
  for (int mt = 0; mt < 2; ++mt)
#pragma unroll
    for (int nt = 0; nt < 8; ++nt) { accL[mt][nt] = zero; accG[mt][nt] = zero; }

  const size_t eBase = (size_t)b * S_DIM * D_DIM;

  for (int kt = 0; kt < NKCH; ++kt) {
    const int k0 = kt * 32;
    if (preconv) {
#pragma unroll
      for (int i = 0; i < 4; ++i) {
        int task = tid + i * 512;
        int s = task >> 2, dg = task & 3;
        bf16x8 v = *reinterpret_cast<const bf16x8*>(Eb + eBase + (size_t)s * D_DIM + k0 + dg * 8);
        *reinterpret_cast<bf16x8*>(&sE[s][dg * 8]) = v;
      }
      {
        int t = tid & 255;
        int r = t >> 2, dg = t & 3;
        const __bf16* src = (tid < 256) ? Qb : Wb;
        bf16x8 v = *reinterpret_cast<const bf16x8*>(src + (size_t)(nbase + r) * D_DIM + k0 + dg * 8);
        __bf16* dst = (tid < 256) ? &sQ[r][dg * 8] : &sC[r][dg * 8];
        *reinterpret_cast<bf16x8*>(dst) = v;
      }
    } else {
#pragma unroll
      for (int i = 0; i < 4; ++i) {
        int task = tid + i * 512;
        int s = task >> 2, dg = task & 3;
        const float* sp = E32 + eBase + (size_t)s * D_DIM + k0 + dg * 8;
        float4 a = *reinterpret_cast<const float4*>(sp);
        float4 c = *reinterpret_cast<const float4*>(sp + 4);
        bf16x8 v;
        v[0] = (__bf16)a.x; v[1] = (__bf16)a.y; v[2] = (__bf16)a.z; v[3] = (__bf16)a.w;
        v[4] = (__bf16)c.x; v[5] = (__bf16)c.y; v[6] = (__bf16)c.z; v[7] = (__bf16)c.w;
        *reinterpret_cast<bf16x8*>(&sE[s][dg * 8]) = v;
      }
      {
        int t = tid & 255;
        int r = t >> 2, dg = t & 3;
        int gr = nbase + r;
        bf16x8 v;
        if (gr < NC) {
          const float* sp = ((tid < 256) ? Q32 : W32) + (size_t)gr * D_DIM + k0 + dg * 8;
          float4 a = *reinterpret_cast<const float4*>(sp);
          float4 c = *reinterpret_cast<const float4*>(sp + 4);
          v[0] = (__bf16)a.x; v[1] = (__bf16)a.y; v[2] = (__bf16)a.z; v[3] = (__bf16)a.w;
          v[4] = (__bf16)c.x; v[5] = (__bf16)c.y; v[6] = (__bf16)c.z; v[7] = (__bf16)c.w;
        } else {
#pragma unroll
          for (int j = 0; j < 8; ++j) v[j] = (__bf16)0.0f;
        }
        __bf16* dst = (tid < 256) ? &sQ[r][dg * 8] : &sC[r][dg * 8];
        *reinterpret_cast<bf16x8*>(dst) = v;
      }
    }
    __syncthreads();

    bf16x8 qf0 = *reinterpret_cast<const bf16x8*>(&sQ[wm * 32 + l15][lg * 8]);
    bf16x8 qf1 = *reinterpret_cast<const bf16x8*>(&sQ[wm * 32 + 16 + l15][lg * 8]);
    bf16x8 cf0 = *reinterpret_cast<const bf16x8*>(&sC[wm * 32 + l15][lg * 8]);
    bf16x8 cf1 = *reinterpret_cast<const bf16x8*>(&sC[wm * 32 + 16 + l15][lg * 8]);

#pragma unroll
    for (int nt = 0; nt < 8; ++nt) {
      bf16x8 bf = *reinterpret_cast<const bf16x8*>(&sE[wsl * 128 + nt * 16 + l15][lg * 8]);
      accL[0][nt] = __builtin_amdgcn_mfma_f32_16x16x32_bf16(qf0, bf, accL[0][nt], 0, 0, 0);
      accL[1][nt] = __builtin_amdgcn_mfma_f32_16x16x32_bf16(qf1, bf, accL[1][nt], 0, 0, 0);
      accG[0][nt] = __builtin_amdgcn_mfma_f32_16x16x32_bf16(cf0, bf, accG[0][nt], 0, 0, 0);
      accG[1][nt] = __builtin_amdgcn_mfma_f32_16x16x32_bf16(cf1, bf, accG[1][nt], 0, 0, 0);
    }
    __syncthreads();
  }

  // ---- softmax over S (rows = codes), fused logits reduction
  const float scale = 0.036084391824351615f; // 1/sqrt(768)
  const float* brow = bias + b * S_DIM;
  float bval[8];
#pragma unroll
  for (int nt = 0; nt < 8; ++nt) bval[nt] = brow[wsl * 128 + nt * 16 + l15];

  float rmax[2][4];
#pragma unroll
  for (int mt = 0; mt < 2; ++mt)
#pragma unroll
    for (int r = 0; r < 4; ++r) rmax[mt][r] = -INFINITY;

#pragma unroll
  for (int mt = 0; mt < 2; ++mt)
#pragma unroll
    for (int nt = 0; nt < 8; ++nt)
#pragma unroll
      for (int r = 0; r < 4; ++r) {
        float v = accL[mt][nt][r] * scale + bval[nt];
        accL[mt][nt][r] = v;
        rmax[mt][r] = fmaxf(rmax[mt][r], v);
      }

#pragma unroll
  for (int mt = 0; mt < 2; ++mt)
#pragma unroll
    for (int r = 0; r < 4; ++r) {
      float v = rmax[mt][r];
      v = fmaxf(v, __shfl_xor(v, 1));
      v = fmaxf(v, __shfl_xor(v, 2));
      v = fmaxf(v, __shfl_xor(v, 4));
      v = fmaxf(v, __shfl_xor(v, 8));
      rmax[mt][r] = v;
    }
  if (l15 == 0) {
#pragma unroll
    for (int mt = 0; mt < 2; ++mt)
#pragma unroll
      for (int r = 0; r < 4; ++r) redA[wsl][wm * 32 + mt * 16 + lg * 4 + r] = rmax[mt][r];
  }
  __syncthreads();

  float gmax[2][4];
#pragma unroll
  for (int mt = 0; mt < 2; ++mt)
#pragma unroll
    for (int r = 0; r < 4; ++r) {
      int row = wm * 32 + mt * 16 + lg * 4 + r;
      gmax[mt][r] = fmaxf(fmaxf(redA[0][row], redA[1][row]), fmaxf(redA[2][row], redA[3][row]));
    }
  __syncthreads(); // all reads of redA done before reuse

  float rsum[2][4], pg[2][4];
#pragma unroll
  for (int mt = 0; mt < 2; ++mt)
#pragma unroll
    for (int r = 0; r < 4; ++r) { rsum[mt][r] = 0.f; pg[mt][r] = 0.f; }

#pragma unroll
  for (int mt = 0; mt < 2; ++mt)
#pragma unroll
    for (int nt = 0; nt < 8; ++nt)
#pragma unroll
      for (int r = 0; r < 4; ++r) {
        float p = __expf(accL[mt][nt][r] - gmax[mt][r]);
        accL[mt][nt][r] = p;
        rsum[mt][r] += p;
        pg[mt][r] += p * accG[mt][nt][r];
      }

#pragma unroll
  for (int mt = 0; mt < 2; ++mt)
#pragma unroll
    for (int r = 0; r < 4; ++r) {
      float s1 = rsum[mt][r], s2 = pg[mt][r];
      s1 += __shfl_xor(s1, 1); s1 += __shfl_xor(s1, 2); s1 += __shfl_xor(s1, 4); s1 += __shfl_xor(s1, 8);
      s2 += __shfl_xor(s2, 1); s2 += __shfl_xor(s2, 2); s2 += __shfl_xor(s2, 4); s2 += __shfl_xor(s2, 8);
      rsum[mt][r] = s1; pg[mt][r] = s2;
    }
  if (l15 == 0) {
#pragma unroll
    for (int mt = 0; mt < 2; ++mt)
#pragma unroll
      for (int r = 0; r < 4; ++r) {
        int row = wm * 32 + mt * 16 + lg * 4 + r;
        redA[wsl][row] = rsum[mt][r];
        redB[wsl][row] = pg[mt][r];
      }
  }
  __syncthreads();

  float inv[2][4];
#pragma unroll
  for (int mt = 0; mt < 2; ++mt)
#pragma unroll
    for (int r = 0; r < 4; ++r) {
      int row = wm * 32 + mt * 16 + lg * 4 + r;
      float st = redA[0][row] + redA[1][row] + redA[2][row] + redA[3][row];
      inv[mt][r] = 1.0f / st;
    }

  // attention weights out: [B, NC, S] after logits [B, NC]
  float* outW = out + (size_t)B_DIM * NC;
#pragma unroll
  for (int mt = 0; mt < 2; ++mt)
#pragma unroll
    for (int r = 0; r < 4; ++r) {
      int gn = nbase + wm * 32 + mt * 16 + lg * 4 + r;
      if (gn < NC) {
        size_t base = ((size_t)b * NC + gn) * S_DIM + wsl * 128 + l15;
        float iv = inv[mt][r];
#pragma unroll
        for (int nt = 0; nt < 8; ++nt) outW[base + nt * 16] = accL[mt][nt][r] * iv;
      }
    }

  if (wsl == 0 && l15 == 0) {
#pragma unroll
    for (int mt = 0; mt < 2; ++mt)
#pragma unroll
      for (int r = 0; r < 4; ++r) {
        int row = wm * 32 + mt * 16 + lg * 4 + r;
        int gn = nbase + row;
        if (gn < NC) {
          float tot = redB[0][row] + redB[1][row] + redB[2][row] + redB[3][row];
          out[(size_t)b * NC + gn] = tot * inv[mt][r];
        }
      }
  }
}

extern "C" void kernel_launch(void* const* d_in, const int* in_sizes, int n_in,
                              void* d_out, int out_size, void* d_ws, size_t ws_size,
                              hipStream_t stream) {
  const float* E32 = (const float*)d_in[0];
  const unsigned char* mraw = (const unsigned char*)d_in[1];
  const float* Q32 = (const float*)d_in[2];
  const float* W32 = (const float*)d_in[3];
  float* out = (float*)d_out;

  char* ws = (char*)d_ws;
  float* bias = (float*)ws;
  __bf16* Eb = (__bf16*)(ws + MASK_BYTES);
  __bf16* Qb = (__bf16*)(ws + MASK_BYTES + (size_t)B_DIM * S_DIM * D_DIM * 2);
  __bf16* Wb = (__bf16*)((char*)Qb + (size_t)N_PAD * D_DIM * 2);
  size_t need = MASK_BYTES + (size_t)B_DIM * S_DIM * D_DIM * 2 + 2 * (size_t)N_PAD * D_DIM * 2;
  int preconv = (ws_size >= need) ? 1 : 0;

  prep_mask_kernel<<<1, 256, 0, stream>>>(mraw, bias);

  if (preconv) {
    long nE = (long)B_DIM * S_DIM * D_DIM;   // 3,145,728
    cvt_kernel<<<(int)(nE / 8 / 256), 256, 0, stream>>>(E32, Eb, nE);
    long nQ = (long)NC * D_DIM;              // 6,851,328
    long nQp = (long)N_PAD * D_DIM;          // 6,881,280
    cvt_kernel<<<(int)(nQp / 8 / 256), 256, 0, stream>>>(Q32, Qb, nQ);
    cvt_kernel<<<(int)(nQp / 8 / 256), 256, 0, stream>>>(W32, Wb, nQ);
  }

  fused_kernel<<<N_TILES * B_DIM, 512, 0, stream>>>(E32, Q32, W32, Eb, Qb, Wb, bias, out, preconv);
}

// Round 2
// 234.402 us; speedup vs baseline: 1.3180x; 1.3180x over previous
//
#include <hip/hip_runtime.h>
#include <hip/hip_bf16.h>
#include <math.h>

typedef __bf16 bf16x8 __attribute__((ext_vector_type(8)));
typedef float f32x4 __attribute__((ext_vector_type(4)));

#define B_DIM 8
#define S_DIM 512
#define D_DIM 768
#define NC 8921
#define N_PAD 8960
#define TILE_N 64
#define N_TILES 140
#define NKCH 24
#define ROWB 64
#define BUFB 32768
#define MASK_BYTES 16384
#define SWZ(a) ((a) ^ ((((unsigned)(a)) >> 3) & 0x30))

typedef const __attribute__((address_space(1))) void* gas1_t;
typedef __attribute__((address_space(3))) void* las3_t;

// ---- mask prep: sniff dtype (bool8 / int32 / float32) and emit 0/-inf bias
__global__ void prep_mask_kernel(const unsigned char* __restrict__ raw, float* __restrict__ bias) {
  __shared__ int s_ms, s_f32;
  int tid = threadIdx.x;
  if (tid == 0) { s_ms = 0; s_f32 = 0; }
  __syncthreads();
  int ms = 0, f32c = 0;
  for (int i = tid; i < B_DIM * S_DIM; i += 256) {
    unsigned char c = raw[i];
    if ((i & 3) != 0 && c != 0) ms++;
    if ((i & 3) == 3 && c == 0x3F) f32c++;
  }
  atomicAdd(&s_ms, ms);
  atomicAdd(&s_f32, f32c);
  __syncthreads();
  int mode = (s_ms == 0) ? 0 : ((s_f32 > 500) ? 2 : 1);
  for (int i = tid; i < B_DIM * S_DIM; i += 256) {
    bool m;
    if (mode == 0)      m = ((const int*)raw)[i] != 0;
    else if (mode == 1) m = raw[i] != 0;
    else                m = ((const float*)raw)[i] != 0.0f;
    bias[i] = m ? 0.0f : -INFINITY;
  }
}

// ---- f32 -> bf16 conversion with zero padding past nvalid (nvalid % 8 == 0)
__global__ void cvt_kernel(const float* __restrict__ src, __bf16* __restrict__ dst, long nvalid) {
  long i = ((long)blockIdx.x * blockDim.x + threadIdx.x) * 8;
  bf16x8 o;
  if (i + 8 <= nvalid) {
    float4 a = *reinterpret_cast<const float4*>(src + i);
    float4 b = *reinterpret_cast<const float4*>(src + i + 4);
    o[0] = (__bf16)a.x; o[1] = (__bf16)a.y; o[2] = (__bf16)a.z; o[3] = (__bf16)a.w;
    o[4] = (__bf16)b.x; o[5] = (__bf16)b.y; o[6] = (__bf16)b.z; o[7] = (__bf16)b.w;
  } else {
#pragma unroll
    for (int j = 0; j < 8; ++j) o[j] = (__bf16)0.0f;
  }
  *reinterpret_cast<bf16x8*>(dst + i) = o;
}

// ---- main fused kernel: double-buffered global_load_lds E staging, swizzled,
//      Q/CW fragments prefetched directly into registers from L2/L3.
__launch_bounds__(512, 2)
__global__ void fused_kernel(const __bf16* __restrict__ Eb, const __bf16* __restrict__ Qb,
                             const __bf16* __restrict__ Wb, const float* __restrict__ bias,
                             float* __restrict__ out) {
  __shared__ __attribute__((aligned(16))) char smem[2 * BUFB];

  const int bid = blockIdx.x;
  const int b = bid & 7;                 // batch == XCD -> E slice L2-resident
  const int nbase = (bid >> 3) * TILE_N;
  const int tid = threadIdx.x;
  const int lane = tid & 63;
  const int wave = tid >> 6;
  const int wm = wave >> 2;              // M half (0..1)
  const int wsl = wave & 3;              // S slice (0..3)
  const int l15 = lane & 15;
  const int lg = lane >> 4;

  f32x4 accL[2][8], accG[2][8];
  f32x4 zero = {0.f, 0.f, 0.f, 0.f};
#pragma unroll
  for (int mt = 0; mt < 2; ++mt)
#pragma unroll
    for (int nt = 0; nt < 8; ++nt) { accL[mt][nt] = zero; accG[mt][nt] = zero; }

  // E staging: per-lane pre-swizzled global source offsets (LDS dest is linear)
  int srcE[4];
#pragma unroll
  for (int j = 0; j < 4; ++j) {
    int phys = (wave * 4 + j) * 1024 + lane * 16;
    int lgo = SWZ(phys);
    srcE[j] = (lgo >> 6) * 1536 + (lgo & 63);
  }
  const char* eSrc = (const char*)Eb + (size_t)b * S_DIM * 1536;

  // E fragment read offsets (swizzled)
  int eOff[8];
#pragma unroll
  for (int nt = 0; nt < 8; ++nt) {
    int a = (wsl * 128 + nt * 16 + l15) * ROWB + lg * 16;
    eOff[nt] = SWZ(a);
  }

  const char* qRow = (const char*)Qb + (size_t)(nbase + wm * 32 + l15) * 1536 + lg * 16;
  const char* cRow = (const char*)Wb + (size_t)(nbase + wm * 32 + l15) * 1536 + lg * 16;

  // ---- prologue: stage chunk 0 into buf0, load frag regs for chunk 0
  bf16x8 qf0c = *(const bf16x8*)(qRow);
  bf16x8 qf1c = *(const bf16x8*)(qRow + 16 * 1536);
  bf16x8 cf0c = *(const bf16x8*)(cRow);
  bf16x8 cf1c = *(const bf16x8*)(cRow + 16 * 1536);
#pragma unroll
  for (int j = 0; j < 4; ++j)
    __builtin_amdgcn_global_load_lds((gas1_t)(eSrc + srcE[j]),
        (las3_t)(smem + (wave * 4 + j) * 1024), 16, 0, 0);
  asm volatile("s_waitcnt vmcnt(0)" ::: "memory");
  __builtin_amdgcn_s_barrier();
  __builtin_amdgcn_sched_barrier(0);

  bf16x8 qf0n, qf1n, cf0n, cf1n;

#define KBODY(T, BUFSEL)                                                              \
  {                                                                                   \
    if ((T) < NKCH - 1) {                                                             \
      const char* qp = qRow + ((T) + 1) * 64;                                         \
      const char* cp = cRow + ((T) + 1) * 64;                                         \
      qf0n = *(const bf16x8*)(qp);                                                    \
      qf1n = *(const bf16x8*)(qp + 16 * 1536);                                        \
      cf0n = *(const bf16x8*)(cp);                                                    \
      cf1n = *(const bf16x8*)(cp + 16 * 1536);                                        \
      const char* es = eSrc + ((T) + 1) * 64;                                         \
      _Pragma("unroll")                                                               \
      for (int j = 0; j < 4; ++j)                                                     \
        __builtin_amdgcn_global_load_lds((gas1_t)(es + srcE[j]),                      \
            (las3_t)(smem + ((BUFSEL) ^ 1) * BUFB + (wave * 4 + j) * 1024), 16, 0, 0);\
      asm volatile("s_waitcnt vmcnt(8)" ::: "memory");                                \
    } else {                                                                          \
      asm volatile("s_waitcnt vmcnt(0)" ::: "memory");                                \
    }                                                                                 \
    __builtin_amdgcn_s_barrier();                                                     \
    __builtin_amdgcn_sched_barrier(0);                                                \
    const char* bufp = smem + (BUFSEL) * BUFB;                                        \
    _Pragma("unroll")                                                                 \
    for (int nt = 0; nt < 8; ++nt) {                                                  \
      bf16x8 bf = *(const bf16x8*)(bufp + eOff[nt]);                                  \
      accL[0][nt] = __builtin_amdgcn_mfma_f32_16x16x32_bf16(qf0c, bf, accL[0][nt], 0, 0, 0); \
      accL[1][nt] = __builtin_amdgcn_mfma_f32_16x16x32_bf16(qf1c, bf, accL[1][nt], 0, 0, 0); \
      accG[0][nt] = __builtin_amdgcn_mfma_f32_16x16x32_bf16(cf0c, bf, accG[0][nt], 0, 0, 0); \
      accG[1][nt] = __builtin_amdgcn_mfma_f32_16x16x32_bf16(cf1c, bf, accG[1][nt], 0, 0, 0); \
    }                                                                                 \
    qf0c = qf0n; qf1c = qf1n; cf0c = cf0n; cf1c = cf1n;                               \
  }

#pragma unroll 1
  for (int tp = 0; tp < NKCH / 2; ++tp) {
    KBODY(tp * 2, 0)
    KBODY(tp * 2 + 1, 1)
  }
#undef KBODY

  // ---- epilogue: softmax over S per code row + fused logits reduction
  __syncthreads();                 // all E reads done; alias reductions onto smem
  float* redA = (float*)smem;      // [4][64]
  float* redB = ((float*)smem) + 256;

  const float scale = 0.036084391824351615f; // 1/sqrt(768)
  const float* brow = bias + b * S_DIM;
  float bval[8];
#pragma unroll
  for (int nt = 0; nt < 8; ++nt) bval[nt] = brow[wsl * 128 + nt * 16 + l15];

  float rmax[2][4];
#pragma unroll
  for (int mt = 0; mt < 2; ++mt)
#pragma unroll
    for (int r = 0; r < 4; ++r) rmax[mt][r] = -INFINITY;

#pragma unroll
  for (int mt = 0; mt < 2; ++mt)
#pragma unroll
    for (int nt = 0; nt < 8; ++nt)
#pragma unroll
      for (int r = 0; r < 4; ++r) {
        float v = accL[mt][nt][r] * scale + bval[nt];
        accL[mt][nt][r] = v;
        rmax[mt][r] = fmaxf(rmax[mt][r], v);
      }

#pragma unroll
  for (int mt = 0; mt < 2; ++mt)
#pragma unroll
    for (int r = 0; r < 4; ++r) {
      float v = rmax[mt][r];
      v = fmaxf(v, __shfl_xor(v, 1));
      v = fmaxf(v, __shfl_xor(v, 2));
      v = fmaxf(v, __shfl_xor(v, 4));
      v = fmaxf(v, __shfl_xor(v, 8));
      rmax[mt][r] = v;
    }
  if (l15 == 0) {
#pragma unroll
    for (int mt = 0; mt < 2; ++mt)
#pragma unroll
      for (int r = 0; r < 4; ++r) redA[wsl * 64 + wm * 32 + mt * 16 + lg * 4 + r] = rmax[mt][r];
  }
  __syncthreads();

  float gmax[2][4];
#pragma unroll
  for (int mt = 0; mt < 2; ++mt)
#pragma unroll
    for (int r = 0; r < 4; ++r) {
      int row = wm * 32 + mt * 16 + lg * 4 + r;
      gmax[mt][r] = fmaxf(fmaxf(redA[row], redA[64 + row]), fmaxf(redA[128 + row], redA[192 + row]));
    }
  __syncthreads();

  float rsum[2][4], pg[2][4];
#pragma unroll
  for (int mt = 0; mt < 2; ++mt)
#pragma unroll
    for (int r = 0; r < 4; ++r) { rsum[mt][r] = 0.f; pg[mt][r] = 0.f; }

#pragma unroll
  for (int mt = 0; mt < 2; ++mt)
#pragma unroll
    for (int nt = 0; nt < 8; ++nt)
#pragma unroll
      for (int r = 0; r < 4; ++r) {
        float p = __expf(accL[mt][nt][r] - gmax[mt][r]);
        accL[mt][nt][r] = p;
        rsum[mt][r] += p;
        pg[mt][r] += p * accG[mt][nt][r];
      }

#pragma unroll
  for (int mt = 0; mt < 2; ++mt)
#pragma unroll
    for (int r = 0; r < 4; ++r) {
      float s1 = rsum[mt][r], s2 = pg[mt][r];
      s1 += __shfl_xor(s1, 1); s1 += __shfl_xor(s1, 2); s1 += __shfl_xor(s1, 4); s1 += __shfl_xor(s1, 8);
      s2 += __shfl_xor(s2, 1); s2 += __shfl_xor(s2, 2); s2 += __shfl_xor(s2, 4); s2 += __shfl_xor(s2, 8);
      rsum[mt][r] = s1; pg[mt][r] = s2;
    }
  if (l15 == 0) {
#pragma unroll
    for (int mt = 0; mt < 2; ++mt)
#pragma unroll
      for (int r = 0; r < 4; ++r) {
        int row = wm * 32 + mt * 16 + lg * 4 + r;
        redA[wsl * 64 + row] = rsum[mt][r];
        redB[wsl * 64 + row] = pg[mt][r];
      }
  }
  __syncthreads();

  float inv[2][4];
#pragma unroll
  for (int mt = 0; mt < 2; ++mt)
#pragma unroll
    for (int r = 0; r < 4; ++r) {
      int row = wm * 32 + mt * 16 + lg * 4 + r;
      float st = redA[row] + redA[64 + row] + redA[128 + row] + redA[192 + row];
      inv[mt][r] = 1.0f / st;
    }

  float* outW = out + (size_t)B_DIM * NC;
#pragma unroll
  for (int mt = 0; mt < 2; ++mt)
#pragma unroll
    for (int r = 0; r < 4; ++r) {
      int gn = nbase + wm * 32 + mt * 16 + lg * 4 + r;
      if (gn < NC) {
        size_t base = ((size_t)b * NC + gn) * S_DIM + wsl * 128 + l15;
        float iv = inv[mt][r];
#pragma unroll
        for (int nt = 0; nt < 8; ++nt) outW[base + nt * 16] = accL[mt][nt][r] * iv;
      }
    }

  if (wsl == 0 && l15 == 0) {
#pragma unroll
    for (int mt = 0; mt < 2; ++mt)
#pragma unroll
      for (int r = 0; r < 4; ++r) {
        int row = wm * 32 + mt * 16 + lg * 4 + r;
        int gn = nbase + row;
        if (gn < NC) {
          float tot = redB[row] + redB[64 + row] + redB[128 + row] + redB[192 + row];
          out[(size_t)b * NC + gn] = tot * inv[mt][r];
        }
      }
  }
}

// ---- fallback (ws too small for bf16 preconversion): round-1 f32 reg-staging path
__launch_bounds__(512, 2)
__global__ void fused_fallback(const float* __restrict__ E32, const float* __restrict__ Q32,
                               const float* __restrict__ W32,
                               const float* __restrict__ bias, float* __restrict__ out) {
  __shared__ __attribute__((aligned(16))) __bf16 sE[S_DIM][40];
  __shared__ __attribute__((aligned(16))) __bf16 sQ[TILE_N][40];
  __shared__ __attribute__((aligned(16))) __bf16 sC[TILE_N][40];
  __shared__ float redA[4][TILE_N];
  __shared__ float redB[4][TILE_N];

  const int bid = blockIdx.x;
  const int b = bid & 7;
  const int nbase = (bid >> 3) * TILE_N;
  const int tid = threadIdx.x;
  const int lane = tid & 63;
  const int wave = tid >> 6;
  const int wm = wave >> 2, wsl = wave & 3;
  const int l15 = lane & 15, lg = lane >> 4;

  f32x4 accL[2][8], accG[2][8];
  f32x4 zero = {0.f, 0.f, 0.f, 0.f};
#pragma unroll
  for (int mt = 0; mt < 2; ++mt)
#pragma unroll
    for (int nt = 0; nt < 8; ++nt) { accL[mt][nt] = zero; accG[mt][nt] = zero; }

  const size_t eBase = (size_t)b * S_DIM * D_DIM;

  for (int kt = 0; kt < NKCH; ++kt) {
    const int k0 = kt * 32;
#pragma unroll
    for (int i = 0; i < 4; ++i) {
      int task = tid + i * 512;
      int s = task >> 2, dg = task & 3;
      const float* sp = E32 + eBase + (size_t)s * D_DIM + k0 + dg * 8;
      float4 a = *reinterpret_cast<const float4*>(sp);
      float4 c = *reinterpret_cast<const float4*>(sp + 4);
      bf16x8 v;
      v[0] = (__bf16)a.x; v[1] = (__bf16)a.y; v[2] = (__bf16)a.z; v[3] = (__bf16)a.w;
      v[4] = (__bf16)c.x; v[5] = (__bf16)c.y; v[6] = (__bf16)c.z; v[7] = (__bf16)c.w;
      *reinterpret_cast<bf16x8*>(&sE[s][dg * 8]) = v;
    }
    {
      int t = tid & 255;
      int r = t >> 2, dg = t & 3;
      int gr = nbase + r;
      bf16x8 v;
      if (gr < NC) {
        const float* sp = ((tid < 256) ? Q32 : W32) + (size_t)gr * D_DIM + k0 + dg * 8;
        float4 a = *reinterpret_cast<const float4*>(sp);
        float4 c = *reinterpret_cast<const float4*>(sp + 4);
        v[0] = (__bf16)a.x; v[1] = (__bf16)a.y; v[2] = (__bf16)a.z; v[3] = (__bf16)a.w;
        v[4] = (__bf16)c.x; v[5] = (__bf16)c.y; v[6] = (__bf16)c.z; v[7] = (__bf16)c.w;
      } else {
#pragma unroll
        for (int j = 0; j < 8; ++j) v[j] = (__bf16)0.0f;
      }
      __bf16* dst = (tid < 256) ? &sQ[r][dg * 8] : &sC[r][dg * 8];
      *reinterpret_cast<bf16x8*>(dst) = v;
    }
    __syncthreads();

    bf16x8 qf0 = *reinterpret_cast<const bf16x8*>(&sQ[wm * 32 + l15][lg * 8]);
    bf16x8 qf1 = *reinterpret_cast<const bf16x8*>(&sQ[wm * 32 + 16 + l15][lg * 8]);
    bf16x8 cf0 = *reinterpret_cast<const bf16x8*>(&sC[wm * 32 + l15][lg * 8]);
    bf16x8 cf1 = *reinterpret_cast<const bf16x8*>(&sC[wm * 32 + 16 + l15][lg * 8]);

#pragma unroll
    for (int nt = 0; nt < 8; ++nt) {
      bf16x8 bf = *reinterpret_cast<const bf16x8*>(&sE[wsl * 128 + nt * 16 + l15][lg * 8]);
      accL[0][nt] = __builtin_amdgcn_mfma_f32_16x16x32_bf16(qf0, bf, accL[0][nt], 0, 0, 0);
      accL[1][nt] = __builtin_amdgcn_mfma_f32_16x16x32_bf16(qf1, bf, accL[1][nt], 0, 0, 0);
      accG[0][nt] = __builtin_amdgcn_mfma_f32_16x16x32_bf16(cf0, bf, accG[0][nt], 0, 0, 0);
      accG[1][nt] = __builtin_amdgcn_mfma_f32_16x16x32_bf16(cf1, bf, accG[1][nt], 0, 0, 0);
    }
    __syncthreads();
  }

  const float scale = 0.036084391824351615f;
  const float* brow = bias + b * S_DIM;
  float bval[8];
#pragma unroll
  for (int nt = 0; nt < 8; ++nt) bval[nt] = brow[wsl * 128 + nt * 16 + l15];

  float rmax[2][4];
#pragma unroll
  for (int mt = 0; mt < 2; ++mt)
#pragma unroll
    for (int r = 0; r < 4; ++r) rmax[mt][r] = -INFINITY;
#pragma unroll
  for (int mt = 0; mt < 2; ++mt)
#pragma unroll
    for (int nt = 0; nt < 8; ++nt)
#pragma unroll
      for (int r = 0; r < 4; ++r) {
        float v = accL[mt][nt][r] * scale + bval[nt];
        accL[mt][nt][r] = v;
        rmax[mt][r] = fmaxf(rmax[mt][r], v);
      }
#pragma unroll
  for (int mt = 0; mt < 2; ++mt)
#pragma unroll
    for (int r = 0; r < 4; ++r) {
      float v = rmax[mt][r];
      v = fmaxf(v, __shfl_xor(v, 1)); v = fmaxf(v, __shfl_xor(v, 2));
      v = fmaxf(v, __shfl_xor(v, 4)); v = fmaxf(v, __shfl_xor(v, 8));
      rmax[mt][r] = v;
    }
  if (l15 == 0) {
#pragma unroll
    for (int mt = 0; mt < 2; ++mt)
#pragma unroll
      for (int r = 0; r < 4; ++r) redA[wsl][wm * 32 + mt * 16 + lg * 4 + r] = rmax[mt][r];
  }
  __syncthreads();
  float gmax[2][4];
#pragma unroll
  for (int mt = 0; mt < 2; ++mt)
#pragma unroll
    for (int r = 0; r < 4; ++r) {
      int row = wm * 32 + mt * 16 + lg * 4 + r;
      gmax[mt][r] = fmaxf(fmaxf(redA[0][row], redA[1][row]), fmaxf(redA[2][row], redA[3][row]));
    }
  __syncthreads();
  float rsum[2][4], pg[2][4];
#pragma unroll
  for (int mt = 0; mt < 2; ++mt)
#pragma unroll
    for (int r = 0; r < 4; ++r) { rsum[mt][r] = 0.f; pg[mt][r] = 0.f; }
#pragma unroll
  for (int mt = 0; mt < 2; ++mt)
#pragma unroll
    for (int nt = 0; nt < 8; ++nt)
#pragma unroll
      for (int r = 0; r < 4; ++r) {
        float p = __expf(accL[mt][nt][r] - gmax[mt][r]);
        accL[mt][nt][r] = p;
        rsum[mt][r] += p;
        pg[mt][r] += p * accG[mt][nt][r];
      }
#pragma unroll
  for (int mt = 0; mt < 2; ++mt)
#pragma unroll
    for (int r = 0; r < 4; ++r) {
      float s1 = rsum[mt][r], s2 = pg[mt][r];
      s1 += __shfl_xor(s1, 1); s1 += __shfl_xor(s1, 2); s1 += __shfl_xor(s1, 4); s1 += __shfl_xor(s1, 8);
      s2 += __shfl_xor(s2, 1); s2 += __shfl_xor(s2, 2); s2 += __shfl_xor(s2, 4); s2 += __shfl_xor(s2, 8);
      rsum[mt][r] = s1; pg[mt][r] = s2;
    }
  if (l15 == 0) {
#pragma unroll
    for (int mt = 0; mt < 2; ++mt)
#pragma unroll
      for (int r = 0; r < 4; ++r) {
        int row = wm * 32 + mt * 16 + lg * 4 + r;
        redA[wsl][row] = rsum[mt][r];
        redB[wsl][row] = pg[mt][r];
      }
  }
  __syncthreads();
  float inv[2][4];
#pragma unroll
  for (int mt = 0; mt < 2; ++mt)
#pragma unroll
    for (int r = 0; r < 4; ++r) {
      int row = wm * 32 + mt * 16 + lg * 4 + r;
      float st = redA[0][row] + redA[1][row] + redA[2][row] + redA[3][row];
      inv[mt][r] = 1.0f / st;
    }
  float* outW = out + (size_t)B_DIM * NC;
#pragma unroll
  for (int mt = 0; mt < 2; ++mt)
#pragma unroll
    for (int r = 0; r < 4; ++r) {
      int gn = nbase + wm * 32 + mt * 16 + lg * 4 + r;
      if (gn < NC) {
        size_t base = ((size_t)b * NC + gn) * S_DIM + wsl * 128 + l15;
        float iv = inv[mt][r];
#pragma unroll
        for (int nt = 0; nt < 8; ++nt) outW[base + nt * 16] = accL[mt][nt][r] * iv;
      }
    }
  if (wsl == 0 && l15 == 0) {
#pragma unroll
    for (int mt = 0; mt < 2; ++mt)
#pragma unroll
      for (int r = 0; r < 4; ++r) {
        int row = wm * 32 + mt * 16 + lg * 4 + r;
        int gn = nbase + row;
        if (gn < NC) {
          float tot = redB[0][row] + redB[1][row] + redB[2][row] + redB[3][row];
          out[(size_t)b * NC + gn] = tot * inv[mt][r];
        }
      }
  }
}

extern "C" void kernel_launch(void* const* d_in, const int* in_sizes, int n_in,
                              void* d_out, int out_size, void* d_ws, size_t ws_size,
                              hipStream_t stream) {
  const float* E32 = (const float*)d_in[0];
  const unsigned char* mraw = (const unsigned char*)d_in[1];
  const float* Q32 = (const float*)d_in[2];
  const float* W32 = (const float*)d_in[3];
  float* out = (float*)d_out;

  char* ws = (char*)d_ws;
  float* bias = (float*)ws;
  __bf16* Eb = (__bf16*)(ws + MASK_BYTES);
  __bf16* Qb = (__bf16*)(ws + MASK_BYTES + (size_t)B_DIM * S_DIM * D_DIM * 2);
  __bf16* Wb = (__bf16*)((char*)Qb + (size_t)N_PAD * D_DIM * 2);
  size_t need = MASK_BYTES + (size_t)B_DIM * S_DIM * D_DIM * 2 + 2 * (size_t)N_PAD * D_DIM * 2;
  int preconv = (ws_size >= need) ? 1 : 0;

  prep_mask_kernel<<<1, 256, 0, stream>>>(mraw, bias);

  if (preconv) {
    long nE = (long)B_DIM * S_DIM * D_DIM;
    cvt_kernel<<<(int)(nE / 8 / 256), 256, 0, stream>>>(E32, Eb, nE);
    long nQ = (long)NC * D_DIM;
    long nQp = (long)N_PAD * D_DIM;
    cvt_kernel<<<(int)(nQp / 8 / 256), 256, 0, stream>>>(Q32, Qb, nQ);
    cvt_kernel<<<(int)(nQp / 8 / 256), 256, 0, stream>>>(W32, Wb, nQ);
    fused_kernel<<<N_TILES * B_DIM, 512, 0, stream>>>(Eb, Qb, Wb, bias, out);
  } else {
    fused_fallback<<<N_TILES * B_DIM, 512, 0, stream>>>(E32, Q32, W32, bias, out);
  }
}